// Round 6
// baseline (332.862 us; speedup 1.0000x reference)
//
#include <hip/hip_runtime.h>
#include <math.h>

#define TT 2048
#define LK 769
#define NF 20
#define NS 128
#define NB 18

// ---------------------------------------------------------------------------
// Kernel A: symmetric FIR conv (fwd+bwd averaged == conv with symmetrized
// taps), reflect padding folded into index mirror.
// One wg per (signal, filter-PAIR): pha band p + amp band (9-p) share the
// same LDS signal window (2x FMA per LDS byte). Tap ranges found with a
// shuffle reduction (no LDS atomics). Blocks ordered longest-pair-first.
// ---------------------------------------------------------------------------
__global__ __launch_bounds__(256) void conv_kernel(const float* __restrict__ x,
                                                   const float* __restrict__ ker,
                                                   float* __restrict__ filt) {
  __shared__ __align__(16) float w[2832];   // spad[384..3200) + zero tail
  __shared__ __align__(16) float hs1[784];  // symmetrized pha filter
  __shared__ __align__(16) float hs2[784];  // symmetrized amp filter
  __shared__ int red[4][4];
  const int tid = threadIdx.x;
  const int ord = blockIdx.x;
  const int p = ord / NS;                   // 0..9, longest pair first
  const int n = ord % NS;
  const int o1 = p;                          // pha band
  const int o2 = 10 + (9 - p);               // amp band (short with long)
  const float* xr = x + n * TT;
  for (int j = tid; j < 2832; j += 256) {
    float v = 0.f;
    if (j < 2816) {
      int m = j - 384;              // spad[j+384] -> original index (j+384)-768
      if (m < 0) m = -m;            // reflect (edge excluded)
      if (m > 2047) m = 4094 - m;
      v = xr[m];
    }
    w[j] = v;
  }
  const float* kr1 = ker + o1 * LK;
  const float* kr2 = ker + o2 * LK;
  int k0 = 784, k1 = 0, m0 = 784, m1 = 0;
  for (int k = tid; k < 784; k += 256) {
    float v1 = 0.f, v2 = 0.f;
    if (k < LK) {
      v1 = 0.5f * (kr1[k] + kr1[LK - 1 - k]);
      v2 = 0.5f * (kr2[k] + kr2[LK - 1 - k]);
    }
    hs1[k] = v1;
    hs2[k] = v2;
    if (v1 != 0.f) { k0 = min(k0, k); k1 = max(k1, k + 1); }
    if (v2 != 0.f) { m0 = min(m0, k); m1 = max(m1, k + 1); }
  }
#pragma unroll
  for (int off = 32; off > 0; off >>= 1) {
    k0 = min(k0, __shfl_down(k0, off));
    k1 = max(k1, __shfl_down(k1, off));
    m0 = min(m0, __shfl_down(m0, off));
    m1 = max(m1, __shfl_down(m1, off));
  }
  const int wid = tid >> 6;
  if ((tid & 63) == 0) { red[wid][0] = k0; red[wid][1] = k1; red[wid][2] = m0; red[wid][3] = m1; }
  __syncthreads();
  k0 = min(min(red[0][0], red[1][0]), min(red[2][0], red[3][0]));
  k1 = max(max(red[0][1], red[1][1]), max(red[2][1], red[3][1]));
  m0 = min(min(red[0][2], red[1][2]), min(red[2][2], red[3][2]));
  m1 = max(max(red[0][3], red[1][3]), max(red[2][3], red[3][3]));
  const int A0 = __builtin_amdgcn_readfirstlane(k0 & ~3);
  const int A1 = __builtin_amdgcn_readfirstlane((k1 + 3) & ~3);
  const int B0 = __builtin_amdgcn_readfirstlane(m0 & ~3);
  const int B1 = __builtin_amdgcn_readfirstlane((m1 + 3) & ~3);
  const int U0 = min(A0, B0);
  const int U1 = max(A1, B1);

  const int bA = 4 * tid;           // group A outputs [bA, bA+4)
  const int bB = 1024 + 4 * tid;    // group B outputs [bB, bB+4)
  float acc1A[4], acc1B[4], acc2A[4], acc2B[4];
#pragma unroll
  for (int r = 0; r < 4; ++r) { acc1A[r] = 0.f; acc1B[r] = 0.f; acc2A[r] = 0.f; acc2B[r] = 0.f; }
  if (U0 < U1) {
    float4 a0 = *(const float4*)&w[bA + U0];
    float4 a1 = *(const float4*)&w[bA + U0 + 4];
    float4 b0 = *(const float4*)&w[bB + U0];
    float4 b1 = *(const float4*)&w[bB + U0 + 4];
    float4 hv1 = *(const float4*)&hs1[U0];
    float4 hv2 = *(const float4*)&hs2[U0];
    for (int k = U0; k < U1; k += 4) {
      float4 hv1n = *(const float4*)&hs1[k + 4];   // prefetch next taps
      float4 hv2n = *(const float4*)&hs2[k + 4];
      float4 a2 = *(const float4*)&w[bA + k + 8];  // prefetch next window
      float4 b2 = *(const float4*)&w[bB + k + 8];
      float wa[7] = {a0.x, a0.y, a0.z, a0.w, a1.x, a1.y, a1.z};
      float wb[7] = {b0.x, b0.y, b0.z, b0.w, b1.x, b1.y, b1.z};
      if (k >= A0 && k < A1) {
#pragma unroll
        for (int r = 0; r < 4; ++r) {
          acc1A[r] = fmaf(hv1.x, wa[r],     acc1A[r]);
          acc1A[r] = fmaf(hv1.y, wa[r + 1], acc1A[r]);
          acc1A[r] = fmaf(hv1.z, wa[r + 2], acc1A[r]);
          acc1A[r] = fmaf(hv1.w, wa[r + 3], acc1A[r]);
          acc1B[r] = fmaf(hv1.x, wb[r],     acc1B[r]);
          acc1B[r] = fmaf(hv1.y, wb[r + 1], acc1B[r]);
          acc1B[r] = fmaf(hv1.z, wb[r + 2], acc1B[r]);
          acc1B[r] = fmaf(hv1.w, wb[r + 3], acc1B[r]);
        }
      }
      if (k >= B0 && k < B1) {
#pragma unroll
        for (int r = 0; r < 4; ++r) {
          acc2A[r] = fmaf(hv2.x, wa[r],     acc2A[r]);
          acc2A[r] = fmaf(hv2.y, wa[r + 1], acc2A[r]);
          acc2A[r] = fmaf(hv2.z, wa[r + 2], acc2A[r]);
          acc2A[r] = fmaf(hv2.w, wa[r + 3], acc2A[r]);
          acc2B[r] = fmaf(hv2.x, wb[r],     acc2B[r]);
          acc2B[r] = fmaf(hv2.y, wb[r + 1], acc2B[r]);
          acc2B[r] = fmaf(hv2.z, wb[r + 2], acc2B[r]);
          acc2B[r] = fmaf(hv2.w, wb[r + 3], acc2B[r]);
        }
      }
      a0 = a1; a1 = a2;
      b0 = b1; b1 = b2;
      hv1 = hv1n; hv2 = hv2n;
    }
  }
  float* out1 = filt + ((size_t)n * NF + o1) * TT;
  float* out2 = filt + ((size_t)n * NF + o2) * TT;
  *(float4*)&out1[bA] = make_float4(acc1A[0], acc1A[1], acc1A[2], acc1A[3]);
  *(float4*)&out1[bB] = make_float4(acc1B[0], acc1B[1], acc1B[2], acc1B[3]);
  *(float4*)&out2[bA] = make_float4(acc2A[0], acc2A[1], acc2A[2], acc2A[3]);
  *(float4*)&out2[bB] = make_float4(acc2B[0], acc2B[1], acc2B[2], acc2B[3]);
}

// ---------------------------------------------------------------------------
// Kernel B: Hilbert for TWO real rows per block via one complex FFT.
//   w = IFFT(mask * FFT(x1 + i*x2)) = z1 + i*z2  (mask is linear)
//   Re(z)=x exactly  =>  h1 = Im(w) - x2,  h2 = x1 - Re(w)
// Forward DIF (natural -> bit-reversed) + true inverse DIT (bit-reversed ->
// natural); the Hilbert mask is applied IN BIT-REVERSED SPACE where it is a
// pure parity rule: pos 0,1 -> x1; even -> x2; odd>=3 -> 0.
// ---------------------------------------------------------------------------
__global__ __launch_bounds__(256) void hilbert_kernel(float* __restrict__ filt) {
  __shared__ float re[TT], im[TT];
  __shared__ float twr[TT], twi[TT];   // tw[half+j] = exp(-i*pi*j/half)
  const int tid = threadIdx.x;
  const int blk = blockIdx.x;          // rows 2*blk, 2*blk+1
  float* row1 = filt + (size_t)(2 * blk) * TT;
  float* row2 = row1 + TT;
  for (int i = tid; i < TT; i += 256) {
    if (i == 0) { twr[0] = 1.f; twi[0] = 0.f; }
    else {
      int half = 1 << (31 - __clz(i));
      int j = i - half;
      float ang = -3.14159265358979323846f * (float)j / (float)half;
      float s, c;
      sincosf(ang, &s, &c);
      twr[i] = c; twi[i] = s;
    }
    re[i] = row1[i];
    im[i] = row2[i];
  }
  __syncthreads();
  // ---- forward DIF: half = 1024 .. 1, output in bit-reversed order ----
  for (int half = 1024; half >= 1; half >>= 1) {
    for (int bf = tid; bf < 1024; bf += 256) {
      const int j = bf & (half - 1);
      const int i0 = ((bf & ~(half - 1)) << 1) + j;
      const int i1 = i0 + half;
      const float c = twr[half + j], s = twi[half + j];
      float ur = re[i0], ui = im[i0];
      float vr = re[i1], vi = im[i1];
      re[i0] = ur + vr; im[i0] = ui + vi;
      float dr = ur - vr, di = ui - vi;
      re[i1] = fmaf(c, dr, -(s * di));
      im[i1] = fmaf(c, di, s * dr);
    }
    __syncthreads();
  }
  // ---- Hilbert mask in bit-reversed space ----
  for (int jj = tid; jj < TT; jj += 256) {
    if (jj >= 2) {
      if (jj & 1) { re[jj] = 0.f; im[jj] = 0.f; }
      else        { re[jj] *= 2.f; im[jj] *= 2.f; }
    }
  }
  __syncthreads();
  // ---- inverse DIT: half = 1 .. 1024, bit-reversed in -> natural out ----
  for (int half = 1; half <= 1024; half <<= 1) {
    for (int bf = tid; bf < 1024; bf += 256) {
      const int j = bf & (half - 1);
      const int i0 = ((bf & ~(half - 1)) << 1) + j;
      const int i1 = i0 + half;
      const float c = twr[half + j], s = twi[half + j];  // use conj -> e^{+i}
      float vr = re[i1], vi = im[i1];
      float tr = fmaf(c, vr, s * vi);
      float ti = fmaf(c, vi, -(s * vr));
      float ur = re[i0], ui = im[i0];
      re[i0] = ur + tr; im[i0] = ui + ti;
      re[i1] = ur - tr; im[i1] = ui - ti;
    }
    __syncthreads();
  }
  // ---- recover h1,h2; write phase/amp ----
  const int o1 = (2 * blk) % NF;       // even -> pair never crosses pha/amp
  const bool p1 = o1 < 10, p2 = (o1 + 1) < 10;
  const float invN = 1.0f / 2048.0f;
  for (int t = tid; t < TT; t += 256) {
    float x1 = row1[t], x2 = row2[t];
    float wr = re[t] * invN, wi = im[t] * invN;
    float h1 = wi - x2;
    float h2 = x1 - wr;
    row1[t] = p1 ? atan2f(h1, x1) : sqrtf(fmaf(x1, x1, h1 * h1));
    row2[t] = p2 ? atan2f(h2, x2) : sqrtf(fmaf(x2, x2, h2 * h2));
  }
}

// ---------------------------------------------------------------------------
// Kernel C: binned MI with the reference's RESHAPE-SCRAMBLED pairing.
// (see round-2 notes). 320 threads: a = tid>>5 (amp band), sl = tid&31, so
// each 32-lane half-wave reads 128B contiguous from its amp row (coalesced).
// Accumulation uses LDS atomicAdd -> fire-and-forget ds_add_f32: no
// ds_read/lgkmcnt-wait/ds_write chain (that chain made R5 latency-bound,
// VALUBusy 10%). Bins remain thread-private; atomics are incidental.
// ---------------------------------------------------------------------------
__global__ __launch_bounds__(320) void mi_kernel(const float* __restrict__ filt,
                                                 float* __restrict__ mi) {
  __shared__ int idx[TT];
  __shared__ float bins[320 * 19];
  __shared__ float cnt[32 * 19];
  __shared__ float asum[10 * 19];
  __shared__ float csum[19];
  const int tid = threadIdx.x;
  const int blk = blockIdx.x;           // bc*40 + jp
  const int bc = blk / 40, jp = blk % 40;
  for (int i = tid; i < 320 * 19; i += 320) bins[i] = 0.f;
  for (int i = tid; i < 32 * 19; i += 320) cnt[i] = 0.f;
  const float* ph = filt + ((size_t)(bc * 4 + jp / 10) * NF + (jp % 10)) * TT;
  for (int t = tid; t < TT; t += 320) {
    float v = ph[t];
    int b = (int)floorf((v + 3.14159274f) / 6.2831855f * 18.0f);
    b = b < 0 ? 0 : (b > 17 ? 17 : b);
    idx[t] = b;
  }
  __syncthreads();
  {
    const int a = tid >> 5, sl = tid & 31;   // a = a' (output amp index)
    const int ja = (jp & 3) + 4 * a;         // scrambled amp row, same s'
    const float* am = filt + ((size_t)(bc * 4 + ja / 10) * NF + 10 + (ja % 10)) * TT;
    float* bp = &bins[tid * 19];
    if (a == 0) {
      float* cp = &cnt[sl * 19];
      for (int t = sl; t < TT; t += 32) {
        int b = idx[t];
        atomicAdd(&bp[b], am[t]);   // ds_add_f32, no return -> no wait chain
        atomicAdd(&cp[b], 1.f);
      }
    } else {
      for (int t = sl; t < TT; t += 32) {
        int b = idx[t];
        atomicAdd(&bp[b], am[t]);
      }
    }
  }
  __syncthreads();
  if (tid < 180) {
    const int a = tid / 18, b = tid % 18;
    float s = 0.f;
    for (int sl = 0; sl < 32; ++sl) s += bins[(a * 32 + sl) * 19 + b];
    asum[a * 19 + b] = s;
  }
  if (tid >= 192 && tid < 210) {
    const int b = tid - 192;
    float s = 0.f;
    for (int sl = 0; sl < 32; ++sl) s += cnt[sl * 19 + b];
    csum[b] = s;
  }
  __syncthreads();
  if (tid < 10) {
    float tot = 0.f, m[18];
#pragma unroll
    for (int b = 0; b < 18; ++b) {
      float mb = asum[tid * 19 + b] / fmaxf(csum[b], 1.0f);
      m[b] = mb; tot += mb;
    }
    tot = fmaxf(tot, 1e-12f);
    float s = 0.f;
#pragma unroll
    for (int b = 0; b < 18; ++b) {
      float pb = m[b] / tot;
      s += pb * logf(fmaxf(pb, 1e-12f));
    }
    const float LOGN = 2.8903717578961645f; // log(18)
    mi[(size_t)blk * 10 + tid] = (LOGN + s) / LOGN;
  }
}

// ---------------------------------------------------------------------------
// Kernel D: mean over the scrambled s' axis -> out (4,8,10,10)
// ---------------------------------------------------------------------------
__global__ void out_kernel(const float* __restrict__ mi, float* __restrict__ out) {
  int i = blockIdx.x * 256 + threadIdx.x;
  if (i < 3200) {
    int a = i % 10, p = (i / 10) % 10, bc = i / 100;
    float s = 0.f;
    for (int sp = 0; sp < 4; ++sp)
      s += mi[((size_t)(bc * 40 + p * 4 + sp)) * 10 + a];
    out[i] = 0.25f * s;
  }
}

extern "C" void kernel_launch(void* const* d_in, const int* in_sizes, int n_in,
                              void* d_out, int out_size, void* d_ws, size_t ws_size,
                              hipStream_t stream) {
  (void)in_sizes; (void)n_in; (void)out_size; (void)ws_size;
  const float* x = (const float*)d_in[0];     // (4,8,4,2048) fp32
  const float* ker = (const float*)d_in[1];   // (20,769) fp32
  float* out = (float*)d_out;                 // 3200 fp32
  float* filt = (float*)d_ws;                 // 128*20*2048 fp32 (~21 MB)
  float* mi = filt + (size_t)NS * NF * TT;    // 12800 fp32

  conv_kernel<<<NS * 10, 256, 0, stream>>>(x, ker, filt);
  hilbert_kernel<<<NS * NF / 2, 256, 0, stream>>>(filt);
  mi_kernel<<<32 * 40, 320, 0, stream>>>(filt, mi);
  out_kernel<<<(3200 + 255) / 256, 256, 0, stream>>>(mi, out);
}

// Round 7
// 204.970 us; speedup vs baseline: 1.6240x; 1.6240x over previous
//
#include <hip/hip_runtime.h>
#include <math.h>

#define TT 2048
#define LK 769
#define NF 20
#define NS 128
#define NB 18

// ---------------------------------------------------------------------------
// Kernel A: symmetric FIR conv (fwd+bwd averaged == conv with symmetrized
// taps), reflect padding folded into index mirror.
// One wg per (signal, filter-PAIR): pha band p + amp band (9-p) share the
// same LDS signal window (2x FMA per LDS byte). Tap ranges found with a
// shuffle reduction (no LDS atomics). Blocks ordered longest-pair-first.
// ---------------------------------------------------------------------------
__global__ __launch_bounds__(256) void conv_kernel(const float* __restrict__ x,
                                                   const float* __restrict__ ker,
                                                   float* __restrict__ filt) {
  __shared__ __align__(16) float w[2832];   // spad[384..3200) + zero tail
  __shared__ __align__(16) float hs1[784];  // symmetrized pha filter
  __shared__ __align__(16) float hs2[784];  // symmetrized amp filter
  __shared__ int red[4][4];
  const int tid = threadIdx.x;
  const int ord = blockIdx.x;
  const int p = ord / NS;                   // 0..9, longest pair first
  const int n = ord % NS;
  const int o1 = p;                          // pha band
  const int o2 = 10 + (9 - p);               // amp band (short with long)
  const float* xr = x + n * TT;
  for (int j = tid; j < 2832; j += 256) {
    float v = 0.f;
    if (j < 2816) {
      int m = j - 384;              // spad[j+384] -> original index (j+384)-768
      if (m < 0) m = -m;            // reflect (edge excluded)
      if (m > 2047) m = 4094 - m;
      v = xr[m];
    }
    w[j] = v;
  }
  const float* kr1 = ker + o1 * LK;
  const float* kr2 = ker + o2 * LK;
  int k0 = 784, k1 = 0, m0 = 784, m1 = 0;
  for (int k = tid; k < 784; k += 256) {
    float v1 = 0.f, v2 = 0.f;
    if (k < LK) {
      v1 = 0.5f * (kr1[k] + kr1[LK - 1 - k]);
      v2 = 0.5f * (kr2[k] + kr2[LK - 1 - k]);
    }
    hs1[k] = v1;
    hs2[k] = v2;
    if (v1 != 0.f) { k0 = min(k0, k); k1 = max(k1, k + 1); }
    if (v2 != 0.f) { m0 = min(m0, k); m1 = max(m1, k + 1); }
  }
#pragma unroll
  for (int off = 32; off > 0; off >>= 1) {
    k0 = min(k0, __shfl_down(k0, off));
    k1 = max(k1, __shfl_down(k1, off));
    m0 = min(m0, __shfl_down(m0, off));
    m1 = max(m1, __shfl_down(m1, off));
  }
  const int wid = tid >> 6;
  if ((tid & 63) == 0) { red[wid][0] = k0; red[wid][1] = k1; red[wid][2] = m0; red[wid][3] = m1; }
  __syncthreads();
  k0 = min(min(red[0][0], red[1][0]), min(red[2][0], red[3][0]));
  k1 = max(max(red[0][1], red[1][1]), max(red[2][1], red[3][1]));
  m0 = min(min(red[0][2], red[1][2]), min(red[2][2], red[3][2]));
  m1 = max(max(red[0][3], red[1][3]), max(red[2][3], red[3][3]));
  const int A0 = __builtin_amdgcn_readfirstlane(k0 & ~3);
  const int A1 = __builtin_amdgcn_readfirstlane((k1 + 3) & ~3);
  const int B0 = __builtin_amdgcn_readfirstlane(m0 & ~3);
  const int B1 = __builtin_amdgcn_readfirstlane((m1 + 3) & ~3);
  const int U0 = min(A0, B0);
  const int U1 = max(A1, B1);

  const int bA = 4 * tid;           // group A outputs [bA, bA+4)
  const int bB = 1024 + 4 * tid;    // group B outputs [bB, bB+4)
  float acc1A[4], acc1B[4], acc2A[4], acc2B[4];
#pragma unroll
  for (int r = 0; r < 4; ++r) { acc1A[r] = 0.f; acc1B[r] = 0.f; acc2A[r] = 0.f; acc2B[r] = 0.f; }
  if (U0 < U1) {
    float4 a0 = *(const float4*)&w[bA + U0];
    float4 a1 = *(const float4*)&w[bA + U0 + 4];
    float4 b0 = *(const float4*)&w[bB + U0];
    float4 b1 = *(const float4*)&w[bB + U0 + 4];
    float4 hv1 = *(const float4*)&hs1[U0];
    float4 hv2 = *(const float4*)&hs2[U0];
    for (int k = U0; k < U1; k += 4) {
      float4 hv1n = *(const float4*)&hs1[k + 4];   // prefetch next taps
      float4 hv2n = *(const float4*)&hs2[k + 4];
      float4 a2 = *(const float4*)&w[bA + k + 8];  // prefetch next window
      float4 b2 = *(const float4*)&w[bB + k + 8];
      float wa[7] = {a0.x, a0.y, a0.z, a0.w, a1.x, a1.y, a1.z};
      float wb[7] = {b0.x, b0.y, b0.z, b0.w, b1.x, b1.y, b1.z};
      if (k >= A0 && k < A1) {
#pragma unroll
        for (int r = 0; r < 4; ++r) {
          acc1A[r] = fmaf(hv1.x, wa[r],     acc1A[r]);
          acc1A[r] = fmaf(hv1.y, wa[r + 1], acc1A[r]);
          acc1A[r] = fmaf(hv1.z, wa[r + 2], acc1A[r]);
          acc1A[r] = fmaf(hv1.w, wa[r + 3], acc1A[r]);
          acc1B[r] = fmaf(hv1.x, wb[r],     acc1B[r]);
          acc1B[r] = fmaf(hv1.y, wb[r + 1], acc1B[r]);
          acc1B[r] = fmaf(hv1.z, wb[r + 2], acc1B[r]);
          acc1B[r] = fmaf(hv1.w, wb[r + 3], acc1B[r]);
        }
      }
      if (k >= B0 && k < B1) {
#pragma unroll
        for (int r = 0; r < 4; ++r) {
          acc2A[r] = fmaf(hv2.x, wa[r],     acc2A[r]);
          acc2A[r] = fmaf(hv2.y, wa[r + 1], acc2A[r]);
          acc2A[r] = fmaf(hv2.z, wa[r + 2], acc2A[r]);
          acc2A[r] = fmaf(hv2.w, wa[r + 3], acc2A[r]);
          acc2B[r] = fmaf(hv2.x, wb[r],     acc2B[r]);
          acc2B[r] = fmaf(hv2.y, wb[r + 1], acc2B[r]);
          acc2B[r] = fmaf(hv2.z, wb[r + 2], acc2B[r]);
          acc2B[r] = fmaf(hv2.w, wb[r + 3], acc2B[r]);
        }
      }
      a0 = a1; a1 = a2;
      b0 = b1; b1 = b2;
      hv1 = hv1n; hv2 = hv2n;
    }
  }
  float* out1 = filt + ((size_t)n * NF + o1) * TT;
  float* out2 = filt + ((size_t)n * NF + o2) * TT;
  *(float4*)&out1[bA] = make_float4(acc1A[0], acc1A[1], acc1A[2], acc1A[3]);
  *(float4*)&out1[bB] = make_float4(acc1B[0], acc1B[1], acc1B[2], acc1B[3]);
  *(float4*)&out2[bA] = make_float4(acc2A[0], acc2A[1], acc2A[2], acc2A[3]);
  *(float4*)&out2[bB] = make_float4(acc2B[0], acc2B[1], acc2B[2], acc2B[3]);
}

// ---------------------------------------------------------------------------
// Kernel B: Hilbert for TWO real rows per block via one complex FFT.
//   w = IFFT(mask * FFT(x1 + i*x2)) = z1 + i*z2  (mask is linear)
//   Re(z)=x exactly  =>  h1 = Im(w) - x2,  h2 = x1 - Re(w)
// Forward DIF (natural -> bit-reversed) + true inverse DIT (bit-reversed ->
// natural); the Hilbert mask is applied IN BIT-REVERSED SPACE where it is a
// pure parity rule: pos 0,1 -> x1; even -> x2; odd>=3 -> 0.
// ---------------------------------------------------------------------------
__global__ __launch_bounds__(256) void hilbert_kernel(float* __restrict__ filt) {
  __shared__ float re[TT], im[TT];
  __shared__ float twr[TT], twi[TT];   // tw[half+j] = exp(-i*pi*j/half)
  const int tid = threadIdx.x;
  const int blk = blockIdx.x;          // rows 2*blk, 2*blk+1
  float* row1 = filt + (size_t)(2 * blk) * TT;
  float* row2 = row1 + TT;
  for (int i = tid; i < TT; i += 256) {
    if (i == 0) { twr[0] = 1.f; twi[0] = 0.f; }
    else {
      int half = 1 << (31 - __clz(i));
      int j = i - half;
      float ang = -3.14159265358979323846f * (float)j / (float)half;
      float s, c;
      sincosf(ang, &s, &c);
      twr[i] = c; twi[i] = s;
    }
    re[i] = row1[i];
    im[i] = row2[i];
  }
  __syncthreads();
  // ---- forward DIF: half = 1024 .. 1, output in bit-reversed order ----
  for (int half = 1024; half >= 1; half >>= 1) {
    for (int bf = tid; bf < 1024; bf += 256) {
      const int j = bf & (half - 1);
      const int i0 = ((bf & ~(half - 1)) << 1) + j;
      const int i1 = i0 + half;
      const float c = twr[half + j], s = twi[half + j];
      float ur = re[i0], ui = im[i0];
      float vr = re[i1], vi = im[i1];
      re[i0] = ur + vr; im[i0] = ui + vi;
      float dr = ur - vr, di = ui - vi;
      re[i1] = fmaf(c, dr, -(s * di));
      im[i1] = fmaf(c, di, s * dr);
    }
    __syncthreads();
  }
  // ---- Hilbert mask in bit-reversed space ----
  for (int jj = tid; jj < TT; jj += 256) {
    if (jj >= 2) {
      if (jj & 1) { re[jj] = 0.f; im[jj] = 0.f; }
      else        { re[jj] *= 2.f; im[jj] *= 2.f; }
    }
  }
  __syncthreads();
  // ---- inverse DIT: half = 1 .. 1024, bit-reversed in -> natural out ----
  for (int half = 1; half <= 1024; half <<= 1) {
    for (int bf = tid; bf < 1024; bf += 256) {
      const int j = bf & (half - 1);
      const int i0 = ((bf & ~(half - 1)) << 1) + j;
      const int i1 = i0 + half;
      const float c = twr[half + j], s = twi[half + j];  // use conj -> e^{+i}
      float vr = re[i1], vi = im[i1];
      float tr = fmaf(c, vr, s * vi);
      float ti = fmaf(c, vi, -(s * vr));
      float ur = re[i0], ui = im[i0];
      re[i0] = ur + tr; im[i0] = ui + ti;
      re[i1] = ur - tr; im[i1] = ui - ti;
    }
    __syncthreads();
  }
  // ---- recover h1,h2; write phase/amp ----
  const int o1 = (2 * blk) % NF;       // even -> pair never crosses pha/amp
  const bool p1 = o1 < 10, p2 = (o1 + 1) < 10;
  const float invN = 1.0f / 2048.0f;
  for (int t = tid; t < TT; t += 256) {
    float x1 = row1[t], x2 = row2[t];
    float wr = re[t] * invN, wi = im[t] * invN;
    float h1 = wi - x2;
    float h2 = x1 - wr;
    row1[t] = p1 ? atan2f(h1, x1) : sqrtf(fmaf(x1, x1, h1 * h1));
    row2[t] = p2 ? atan2f(h2, x2) : sqrtf(fmaf(x2, x2, h2 * h2));
  }
}

// ---------------------------------------------------------------------------
// Kernel C: binned MI, DENSE register accumulation (no LDS scatter).
// R5 (LDS RMW chain) = 89us latency-bound; R6 (ds_add_f32) = 192us: LDS
// atomic RMW throughput is worse than the chain. Both scatter forms lose.
// Here: thread = (a'=tid>>5, sl=tid&31); 18 register accumulators, 18
// predicated adds per element (branch-free, 18 independent dep chains),
// then __shfl_xor butterfly over the 32-lane half-wave. Counts likewise
// (a'==0 only). Scrambled pairing as per round-2 notes.
// ---------------------------------------------------------------------------
__global__ __launch_bounds__(320) void mi_kernel(const float* __restrict__ filt,
                                                 float* __restrict__ mi) {
  __shared__ int idx[TT];
  __shared__ float asum[10 * 19];
  __shared__ float csum[19];
  const int tid = threadIdx.x;
  const int blk = blockIdx.x;           // bc*40 + jp
  const int bc = blk / 40, jp = blk % 40;
  const float* ph = filt + ((size_t)(bc * 4 + jp / 10) * NF + (jp % 10)) * TT;
  for (int t = tid; t < TT; t += 320) {
    float v = ph[t];
    int b = (int)floorf((v + 3.14159274f) / 6.2831855f * 18.0f);
    b = b < 0 ? 0 : (b > 17 ? 17 : b);
    idx[t] = b;
  }
  __syncthreads();
  const int a = tid >> 5, sl = tid & 31;   // a = a' (output amp index)
  const int ja = (jp & 3) + 4 * a;         // scrambled amp row, same s'
  const float* am = filt + ((size_t)(bc * 4 + ja / 10) * NF + 10 + (ja % 10)) * TT;
  float acc[18];
  int cnt[18];
#pragma unroll
  for (int b = 0; b < 18; ++b) { acc[b] = 0.f; cnt[b] = 0; }
  for (int t = sl; t < TT; t += 32) {
    const int b = idx[t];            // lanes read consecutive -> conflict-free
    const float av = am[t];          // half-wave reads 128B contiguous
#pragma unroll
    for (int b0 = 0; b0 < 18; ++b0)
      acc[b0] += (b == b0) ? av : 0.f;
    if (a == 0) {
#pragma unroll
      for (int b0 = 0; b0 < 18; ++b0)
        cnt[b0] += (b == b0) ? 1 : 0;
    }
  }
  // butterfly over the 32-lane half-wave (xor offsets stay within half)
#pragma unroll
  for (int b = 0; b < 18; ++b) {
#pragma unroll
    for (int off = 16; off > 0; off >>= 1)
      acc[b] += __shfl_xor(acc[b], off);
  }
  if (a == 0) {
#pragma unroll
    for (int b = 0; b < 18; ++b) {
#pragma unroll
      for (int off = 16; off > 0; off >>= 1)
        cnt[b] += __shfl_xor(cnt[b], off);
    }
  }
  if (sl == 0) {
#pragma unroll
    for (int b = 0; b < 18; ++b) asum[a * 19 + b] = acc[b];
    if (a == 0) {
#pragma unroll
      for (int b = 0; b < 18; ++b) csum[b] = (float)cnt[b];
    }
  }
  __syncthreads();
  if (tid < 10) {
    float tot = 0.f, m[18];
#pragma unroll
    for (int b = 0; b < 18; ++b) {
      float mb = asum[tid * 19 + b] / fmaxf(csum[b], 1.0f);
      m[b] = mb; tot += mb;
    }
    tot = fmaxf(tot, 1e-12f);
    float s = 0.f;
#pragma unroll
    for (int b = 0; b < 18; ++b) {
      float pb = m[b] / tot;
      s += pb * logf(fmaxf(pb, 1e-12f));
    }
    const float LOGN = 2.8903717578961645f; // log(18)
    mi[(size_t)blk * 10 + tid] = (LOGN + s) / LOGN;
  }
}

// ---------------------------------------------------------------------------
// Kernel D: mean over the scrambled s' axis -> out (4,8,10,10)
// ---------------------------------------------------------------------------
__global__ void out_kernel(const float* __restrict__ mi, float* __restrict__ out) {
  int i = blockIdx.x * 256 + threadIdx.x;
  if (i < 3200) {
    int a = i % 10, p = (i / 10) % 10, bc = i / 100;
    float s = 0.f;
    for (int sp = 0; sp < 4; ++sp)
      s += mi[((size_t)(bc * 40 + p * 4 + sp)) * 10 + a];
    out[i] = 0.25f * s;
  }
}

extern "C" void kernel_launch(void* const* d_in, const int* in_sizes, int n_in,
                              void* d_out, int out_size, void* d_ws, size_t ws_size,
                              hipStream_t stream) {
  (void)in_sizes; (void)n_in; (void)out_size; (void)ws_size;
  const float* x = (const float*)d_in[0];     // (4,8,4,2048) fp32
  const float* ker = (const float*)d_in[1];   // (20,769) fp32
  float* out = (float*)d_out;                 // 3200 fp32
  float* filt = (float*)d_ws;                 // 128*20*2048 fp32 (~21 MB)
  float* mi = filt + (size_t)NS * NF * TT;    // 12800 fp32

  conv_kernel<<<NS * 10, 256, 0, stream>>>(x, ker, filt);
  hilbert_kernel<<<NS * NF / 2, 256, 0, stream>>>(filt);
  mi_kernel<<<32 * 40, 320, 0, stream>>>(filt, mi);
  out_kernel<<<(3200 + 255) / 256, 256, 0, stream>>>(mi, out);
}

// Round 8
// 198.147 us; speedup vs baseline: 1.6799x; 1.0344x over previous
//
#include <hip/hip_runtime.h>
#include <math.h>

#define TT 2048
#define LK 769
#define NF 20
#define NS 128
#define NB 18

// ---------------------------------------------------------------------------
// Kernel A: symmetric FIR conv (fwd+bwd averaged == conv with symmetrized
// taps), reflect padding folded into index mirror.
// One wg per (signal, filter-PAIR): pha band p + amp band (9-p) share the
// same LDS signal window (2x FMA per LDS byte). Tap ranges found with a
// shuffle reduction (no LDS atomics). Blocks ordered longest-pair-first.
// ---------------------------------------------------------------------------
__global__ __launch_bounds__(256) void conv_kernel(const float* __restrict__ x,
                                                   const float* __restrict__ ker,
                                                   float* __restrict__ filt) {
  __shared__ __align__(16) float w[2832];   // spad[384..3200) + zero tail
  __shared__ __align__(16) float hs1[784];  // symmetrized pha filter
  __shared__ __align__(16) float hs2[784];  // symmetrized amp filter
  __shared__ int red[4][4];
  const int tid = threadIdx.x;
  const int ord = blockIdx.x;
  const int p = ord / NS;                   // 0..9, longest pair first
  const int n = ord % NS;
  const int o1 = p;                          // pha band
  const int o2 = 10 + (9 - p);               // amp band (short with long)
  const float* xr = x + n * TT;
  for (int j = tid; j < 2832; j += 256) {
    float v = 0.f;
    if (j < 2816) {
      int m = j - 384;              // spad[j+384] -> original index (j+384)-768
      if (m < 0) m = -m;            // reflect (edge excluded)
      if (m > 2047) m = 4094 - m;
      v = xr[m];
    }
    w[j] = v;
  }
  const float* kr1 = ker + o1 * LK;
  const float* kr2 = ker + o2 * LK;
  int k0 = 784, k1 = 0, m0 = 784, m1 = 0;
  for (int k = tid; k < 784; k += 256) {
    float v1 = 0.f, v2 = 0.f;
    if (k < LK) {
      v1 = 0.5f * (kr1[k] + kr1[LK - 1 - k]);
      v2 = 0.5f * (kr2[k] + kr2[LK - 1 - k]);
    }
    hs1[k] = v1;
    hs2[k] = v2;
    if (v1 != 0.f) { k0 = min(k0, k); k1 = max(k1, k + 1); }
    if (v2 != 0.f) { m0 = min(m0, k); m1 = max(m1, k + 1); }
  }
#pragma unroll
  for (int off = 32; off > 0; off >>= 1) {
    k0 = min(k0, __shfl_down(k0, off));
    k1 = max(k1, __shfl_down(k1, off));
    m0 = min(m0, __shfl_down(m0, off));
    m1 = max(m1, __shfl_down(m1, off));
  }
  const int wid = tid >> 6;
  if ((tid & 63) == 0) { red[wid][0] = k0; red[wid][1] = k1; red[wid][2] = m0; red[wid][3] = m1; }
  __syncthreads();
  k0 = min(min(red[0][0], red[1][0]), min(red[2][0], red[3][0]));
  k1 = max(max(red[0][1], red[1][1]), max(red[2][1], red[3][1]));
  m0 = min(min(red[0][2], red[1][2]), min(red[2][2], red[3][2]));
  m1 = max(max(red[0][3], red[1][3]), max(red[2][3], red[3][3]));
  const int A0 = __builtin_amdgcn_readfirstlane(k0 & ~3);
  const int A1 = __builtin_amdgcn_readfirstlane((k1 + 3) & ~3);
  const int B0 = __builtin_amdgcn_readfirstlane(m0 & ~3);
  const int B1 = __builtin_amdgcn_readfirstlane((m1 + 3) & ~3);
  const int U0 = min(A0, B0);
  const int U1 = max(A1, B1);

  const int bA = 4 * tid;           // group A outputs [bA, bA+4)
  const int bB = 1024 + 4 * tid;    // group B outputs [bB, bB+4)
  float acc1A[4], acc1B[4], acc2A[4], acc2B[4];
#pragma unroll
  for (int r = 0; r < 4; ++r) { acc1A[r] = 0.f; acc1B[r] = 0.f; acc2A[r] = 0.f; acc2B[r] = 0.f; }
  if (U0 < U1) {
    float4 a0 = *(const float4*)&w[bA + U0];
    float4 a1 = *(const float4*)&w[bA + U0 + 4];
    float4 b0 = *(const float4*)&w[bB + U0];
    float4 b1 = *(const float4*)&w[bB + U0 + 4];
    float4 hv1 = *(const float4*)&hs1[U0];
    float4 hv2 = *(const float4*)&hs2[U0];
    for (int k = U0; k < U1; k += 4) {
      float4 hv1n = *(const float4*)&hs1[k + 4];   // prefetch next taps
      float4 hv2n = *(const float4*)&hs2[k + 4];
      float4 a2 = *(const float4*)&w[bA + k + 8];  // prefetch next window
      float4 b2 = *(const float4*)&w[bB + k + 8];
      float wa[7] = {a0.x, a0.y, a0.z, a0.w, a1.x, a1.y, a1.z};
      float wb[7] = {b0.x, b0.y, b0.z, b0.w, b1.x, b1.y, b1.z};
      if (k >= A0 && k < A1) {
#pragma unroll
        for (int r = 0; r < 4; ++r) {
          acc1A[r] = fmaf(hv1.x, wa[r],     acc1A[r]);
          acc1A[r] = fmaf(hv1.y, wa[r + 1], acc1A[r]);
          acc1A[r] = fmaf(hv1.z, wa[r + 2], acc1A[r]);
          acc1A[r] = fmaf(hv1.w, wa[r + 3], acc1A[r]);
          acc1B[r] = fmaf(hv1.x, wb[r],     acc1B[r]);
          acc1B[r] = fmaf(hv1.y, wb[r + 1], acc1B[r]);
          acc1B[r] = fmaf(hv1.z, wb[r + 2], acc1B[r]);
          acc1B[r] = fmaf(hv1.w, wb[r + 3], acc1B[r]);
        }
      }
      if (k >= B0 && k < B1) {
#pragma unroll
        for (int r = 0; r < 4; ++r) {
          acc2A[r] = fmaf(hv2.x, wa[r],     acc2A[r]);
          acc2A[r] = fmaf(hv2.y, wa[r + 1], acc2A[r]);
          acc2A[r] = fmaf(hv2.z, wa[r + 2], acc2A[r]);
          acc2A[r] = fmaf(hv2.w, wa[r + 3], acc2A[r]);
          acc2B[r] = fmaf(hv2.x, wb[r],     acc2B[r]);
          acc2B[r] = fmaf(hv2.y, wb[r + 1], acc2B[r]);
          acc2B[r] = fmaf(hv2.z, wb[r + 2], acc2B[r]);
          acc2B[r] = fmaf(hv2.w, wb[r + 3], acc2B[r]);
        }
      }
      a0 = a1; a1 = a2;
      b0 = b1; b1 = b2;
      hv1 = hv1n; hv2 = hv2n;
    }
  }
  float* out1 = filt + ((size_t)n * NF + o1) * TT;
  float* out2 = filt + ((size_t)n * NF + o2) * TT;
  *(float4*)&out1[bA] = make_float4(acc1A[0], acc1A[1], acc1A[2], acc1A[3]);
  *(float4*)&out1[bB] = make_float4(acc1B[0], acc1B[1], acc1B[2], acc1B[3]);
  *(float4*)&out2[bA] = make_float4(acc2A[0], acc2A[1], acc2A[2], acc2A[3]);
  *(float4*)&out2[bB] = make_float4(acc2B[0], acc2B[1], acc2B[2], acc2B[3]);
}

// ---------------------------------------------------------------------------
// Kernel B: Hilbert for TWO real rows per block via one complex FFT.
//   w = IFFT(mask * FFT(x1 + i*x2)) = z1 + i*z2  (mask is linear)
//   Re(z)=x exactly  =>  h1 = Im(w) - x2,  h2 = x1 - Re(w)
// Forward DIF (natural -> bit-reversed) + true inverse DIT (bit-reversed ->
// natural); the Hilbert mask is applied IN BIT-REVERSED SPACE where it is a
// pure parity rule: pos 0,1 -> x1; even -> x2; odd>=3 -> 0.
// ---------------------------------------------------------------------------
__global__ __launch_bounds__(256) void hilbert_kernel(float* __restrict__ filt) {
  __shared__ float re[TT], im[TT];
  __shared__ float twr[TT], twi[TT];   // tw[half+j] = exp(-i*pi*j/half)
  const int tid = threadIdx.x;
  const int blk = blockIdx.x;          // rows 2*blk, 2*blk+1
  float* row1 = filt + (size_t)(2 * blk) * TT;
  float* row2 = row1 + TT;
  for (int i = tid; i < TT; i += 256) {
    if (i == 0) { twr[0] = 1.f; twi[0] = 0.f; }
    else {
      int half = 1 << (31 - __clz(i));
      int j = i - half;
      float ang = -3.14159265358979323846f * (float)j / (float)half;
      float s, c;
      sincosf(ang, &s, &c);
      twr[i] = c; twi[i] = s;
    }
    re[i] = row1[i];
    im[i] = row2[i];
  }
  __syncthreads();
  // ---- forward DIF: half = 1024 .. 1, output in bit-reversed order ----
  for (int half = 1024; half >= 1; half >>= 1) {
    for (int bf = tid; bf < 1024; bf += 256) {
      const int j = bf & (half - 1);
      const int i0 = ((bf & ~(half - 1)) << 1) + j;
      const int i1 = i0 + half;
      const float c = twr[half + j], s = twi[half + j];
      float ur = re[i0], ui = im[i0];
      float vr = re[i1], vi = im[i1];
      re[i0] = ur + vr; im[i0] = ui + vi;
      float dr = ur - vr, di = ui - vi;
      re[i1] = fmaf(c, dr, -(s * di));
      im[i1] = fmaf(c, di, s * dr);
    }
    __syncthreads();
  }
  // ---- Hilbert mask in bit-reversed space ----
  for (int jj = tid; jj < TT; jj += 256) {
    if (jj >= 2) {
      if (jj & 1) { re[jj] = 0.f; im[jj] = 0.f; }
      else        { re[jj] *= 2.f; im[jj] *= 2.f; }
    }
  }
  __syncthreads();
  // ---- inverse DIT: half = 1 .. 1024, bit-reversed in -> natural out ----
  for (int half = 1; half <= 1024; half <<= 1) {
    for (int bf = tid; bf < 1024; bf += 256) {
      const int j = bf & (half - 1);
      const int i0 = ((bf & ~(half - 1)) << 1) + j;
      const int i1 = i0 + half;
      const float c = twr[half + j], s = twi[half + j];  // use conj -> e^{+i}
      float vr = re[i1], vi = im[i1];
      float tr = fmaf(c, vr, s * vi);
      float ti = fmaf(c, vi, -(s * vr));
      float ur = re[i0], ui = im[i0];
      re[i0] = ur + tr; im[i0] = ui + ti;
      re[i1] = ur - tr; im[i1] = ui - ti;
    }
    __syncthreads();
  }
  // ---- recover h1,h2; write phase/amp ----
  const int o1 = (2 * blk) % NF;       // even -> pair never crosses pha/amp
  const bool p1 = o1 < 10, p2 = (o1 + 1) < 10;
  const float invN = 1.0f / 2048.0f;
  for (int t = tid; t < TT; t += 256) {
    float x1 = row1[t], x2 = row2[t];
    float wr = re[t] * invN, wi = im[t] * invN;
    float h1 = wi - x2;
    float h2 = x1 - wr;
    row1[t] = p1 ? atan2f(h1, x1) : sqrtf(fmaf(x1, x1, h1 * h1));
    row2[t] = p2 ? atan2f(h2, x2) : sqrtf(fmaf(x2, x2, h2 * h2));
  }
}

// ---------------------------------------------------------------------------
// Kernel C: binned MI, dense register accumulation v2.
// Changes vs R7 (63us, VALUBusy 61%):
//  - counts computed in the idx phase (dense per-thread ints, butterfly
//    reduced) -> the 10 sum-warps are uniform (R7's a==0 wave did 90
//    ops/el vs 54 and was every block's critical path)
//  - float4 amp + int4 idx inner loop: load/addr overhead amortized 4x,
//    4 independent element chains of ILP
// Scrambled (reshape) pairing as per round-2 notes.
// ---------------------------------------------------------------------------
__global__ __launch_bounds__(320) void mi_kernel(const float* __restrict__ filt,
                                                 float* __restrict__ mi) {
  __shared__ __align__(16) int idx[TT];
  __shared__ float asum[10 * 19];
  __shared__ int cred[5 * 18];
  __shared__ float csum[18];
  const int tid = threadIdx.x;
  const int blk = blockIdx.x;           // bc*40 + jp
  const int bc = blk / 40, jp = blk % 40;
  const float* ph = filt + ((size_t)(bc * 4 + jp / 10) * NF + (jp % 10)) * TT;
  // ---- phase 1: bin indices + counts (phase-row only) ----
  int myc[18];
#pragma unroll
  for (int b = 0; b < 18; ++b) myc[b] = 0;
  for (int t = tid; t < TT; t += 320) {
    float v = ph[t];
    int b = (int)floorf((v + 3.14159274f) / 6.2831855f * 18.0f);
    b = b < 0 ? 0 : (b > 17 ? 17 : b);
    idx[t] = b;
#pragma unroll
    for (int b0 = 0; b0 < 18; ++b0) myc[b0] += (b == b0) ? 1 : 0;
  }
#pragma unroll
  for (int b = 0; b < 18; ++b) {
#pragma unroll
    for (int off = 32; off > 0; off >>= 1)
      myc[b] += __shfl_xor(myc[b], off);
  }
  if ((tid & 63) == 0) {
    const int wv = tid >> 6;
#pragma unroll
    for (int b = 0; b < 18; ++b) cred[wv * 18 + b] = myc[b];
  }
  __syncthreads();
  if (tid < 18) {
    int s = 0;
#pragma unroll
    for (int wv = 0; wv < 5; ++wv) s += cred[wv * 18 + tid];
    csum[tid] = (float)s;
  }
  // ---- phase 2: dense amp-sum, float4/int4 inner ----
  const int a = tid >> 5, sl = tid & 31;   // a = a' (output amp index)
  const int ja = (jp & 3) + 4 * a;         // scrambled amp row, same s'
  const float* am = filt + ((size_t)(bc * 4 + ja / 10) * NF + 10 + (ja % 10)) * TT;
  float acc[18];
#pragma unroll
  for (int b = 0; b < 18; ++b) acc[b] = 0.f;
#pragma unroll 4
  for (int k = 0; k < 16; ++k) {
    const int base = k * 128 + sl * 4;     // 32 lanes x 16B contiguous
    const float4 av = *(const float4*)&am[base];
    const int4 bx = *(const int4*)&idx[base];
#pragma unroll
    for (int b0 = 0; b0 < 18; ++b0) {
      acc[b0] += (bx.x == b0) ? av.x : 0.f;
      acc[b0] += (bx.y == b0) ? av.y : 0.f;
      acc[b0] += (bx.z == b0) ? av.z : 0.f;
      acc[b0] += (bx.w == b0) ? av.w : 0.f;
    }
  }
  // butterfly over the 32-lane half-wave (xor offsets stay within half)
#pragma unroll
  for (int b = 0; b < 18; ++b) {
#pragma unroll
    for (int off = 16; off > 0; off >>= 1)
      acc[b] += __shfl_xor(acc[b], off);
  }
  if (sl == 0) {
#pragma unroll
    for (int b = 0; b < 18; ++b) asum[a * 19 + b] = acc[b];
  }
  __syncthreads();
  // ---- phase 3: MI ----
  if (tid < 10) {
    float tot = 0.f, m[18];
#pragma unroll
    for (int b = 0; b < 18; ++b) {
      float mb = asum[tid * 19 + b] / fmaxf(csum[b], 1.0f);
      m[b] = mb; tot += mb;
    }
    tot = fmaxf(tot, 1e-12f);
    float s = 0.f;
#pragma unroll
    for (int b = 0; b < 18; ++b) {
      float pb = m[b] / tot;
      s += pb * logf(fmaxf(pb, 1e-12f));
    }
    const float LOGN = 2.8903717578961645f; // log(18)
    mi[(size_t)blk * 10 + tid] = (LOGN + s) / LOGN;
  }
}

// ---------------------------------------------------------------------------
// Kernel D: mean over the scrambled s' axis -> out (4,8,10,10)
// ---------------------------------------------------------------------------
__global__ void out_kernel(const float* __restrict__ mi, float* __restrict__ out) {
  int i = blockIdx.x * 256 + threadIdx.x;
  if (i < 3200) {
    int a = i % 10, p = (i / 10) % 10, bc = i / 100;
    float s = 0.f;
    for (int sp = 0; sp < 4; ++sp)
      s += mi[((size_t)(bc * 40 + p * 4 + sp)) * 10 + a];
    out[i] = 0.25f * s;
  }
}

extern "C" void kernel_launch(void* const* d_in, const int* in_sizes, int n_in,
                              void* d_out, int out_size, void* d_ws, size_t ws_size,
                              hipStream_t stream) {
  (void)in_sizes; (void)n_in; (void)out_size; (void)ws_size;
  const float* x = (const float*)d_in[0];     // (4,8,4,2048) fp32
  const float* ker = (const float*)d_in[1];   // (20,769) fp32
  float* out = (float*)d_out;                 // 3200 fp32
  float* filt = (float*)d_ws;                 // 128*20*2048 fp32 (~21 MB)
  float* mi = filt + (size_t)NS * NF * TT;    // 12800 fp32

  conv_kernel<<<NS * 10, 256, 0, stream>>>(x, ker, filt);
  hilbert_kernel<<<NS * NF / 2, 256, 0, stream>>>(filt);
  mi_kernel<<<32 * 40, 320, 0, stream>>>(filt, mi);
  out_kernel<<<(3200 + 255) / 256, 256, 0, stream>>>(mi, out);
}